// Round 1
// baseline (190.236 us; speedup 1.0000x reference)
//
#include <hip/hip_runtime.h>
#include <math.h>

#define BS 32
#define KP 1000
#define KG 100
#define NC 80
#define NT 16            // ceil(KP/64)
#define NPAIR 136        // NT*(NT+1)/2
#define LSTR 96          // LDS row stride in floats (24 float4 slots; slot = q ^ ((r>>2)&7) <= 23)

__device__ __forceinline__ float wave_reduce_sum(float v) {
#pragma unroll
    for (int m = 32; m > 0; m >>= 1) v += __shfl_xor(v, m, 64);
    return v;
}
__device__ __forceinline__ float wave_reduce_max(float v) {
#pragma unroll
    for (int m = 32; m > 0; m >>= 1) v = fmaxf(v, __shfl_xor(v, m, 64));
    return v;
}

// K_ij = N(m_i; m_j, v_i+v_j) for 2 independent dims.
// a,b = (mx, my, vx, vy)
__device__ __forceinline__ float kval(float4 a, float4 b) {
    float Sx = a.z + b.z, Sy = a.w + b.w;
    float ix = 1.0f / Sx, iy = 1.0f / Sy;
    float dx = a.x - b.x, dy = a.y - b.y;
    return 0.15915494309189535f * sqrtf(ix * iy) *
           __expf(-0.5f * (dx * dx * ix + dy * dy * iy));
}

__global__ void init_kernel(float* __restrict__ acc) {
    if (threadIdx.x < 96) acc[threadIdx.x] = 0.0f;
}

// pred_alpha[row][c] = sigmoid(logits[80]) * softmax(logits[0..79])
// one wave per row; 4 waves (256 threads) per block
__global__ __launch_bounds__(256) void alpha_kernel(const float* __restrict__ pl,
                                                    float* __restrict__ alpha) {
    int wave = threadIdx.x >> 6;
    int lane = threadIdx.x & 63;
    int row = blockIdx.x * 4 + wave;                  // < BS*KP = 32000
    const float* x = pl + (size_t)row * (NC + 1);
    float l0 = x[lane];
    float l1;
    if (lane < 16) l1 = x[64 + lane]; else l1 = -1e30f;
    float obj = x[NC];
    float m = wave_reduce_max(fmaxf(l0, l1));
    float e0 = __expf(l0 - m);
    float e1 = (lane < 16) ? __expf(l1 - m) : 0.0f;
    float s = wave_reduce_sum(e0 + e1);
    float sig = 1.0f / (1.0f + __expf(-obj));
    float sc = sig / s;
    float* o = alpha + (size_t)row * NC;
    o[lane] = e0 * sc;
    if (lane < 16) o[64 + lane] = e1 * sc;
}

// pp: per image, sum over 100x100 gt pairs with w = (label_i == label_j)
__global__ __launch_bounds__(256) void pp_kernel(const float* __restrict__ gtb,
                                                 const int* __restrict__ gtl,
                                                 float* __restrict__ acc_pp) {
    __shared__ float4 gm[KG];
    __shared__ int gl[KG];
    __shared__ float red[256];
    int b = blockIdx.x;
    int tid = threadIdx.x;
    if (tid < KG) {
        float4 x = ((const float4*)gtb)[b * KG + tid];
        float hw = x.z * 0.5f, hh = x.w * 0.5f;
        gm[tid] = make_float4(x.x, x.y, hw * hw, hh * hh);
        gl[tid] = gtl[b * KG + tid];
    }
    __syncthreads();
    float part = 0.0f;
    for (int p = tid; p < KG * KG; p += 256) {
        int i = p / KG;
        int j = p - i * KG;
        if (gl[i] == gl[j]) part += kval(gm[i], gm[j]);
    }
    red[tid] = part;
    __syncthreads();
#pragma unroll
    for (int s = 128; s > 0; s >>= 1) {
        if (tid < s) red[tid] += red[tid + s];
        __syncthreads();
    }
    if (tid == 0) acc_pp[b] = red[0];
}

// pq: per image, sum over 100x1000 (gt i, pred j) pairs, w = alpha[j][label_i]
__global__ __launch_bounds__(256) void pq_kernel(const float* __restrict__ pb,
                                                 const float* __restrict__ alpha,
                                                 const float* __restrict__ gtb,
                                                 const int* __restrict__ gtl,
                                                 float* __restrict__ acc_pq) {
    __shared__ float4 gm[KG];
    __shared__ int gl[KG];
    __shared__ float red[256];
    int b = blockIdx.y;
    int tid = threadIdx.x;
    if (tid < KG) {
        float4 x = ((const float4*)gtb)[b * KG + tid];
        float hw = x.z * 0.5f, hh = x.w * 0.5f;
        gm[tid] = make_float4(x.x, x.y, hw * hw, hh * hh);
        gl[tid] = gtl[b * KG + tid];
    }
    __syncthreads();
    int j = blockIdx.x * 256 + tid;
    float part = 0.0f;
    if (j < KP) {
        float4 x = ((const float4*)pb)[b * KP + j];
        float hw = x.z * 0.5f, hh = x.w * 0.5f;
        float4 pm = make_float4(x.x, x.y, hw * hw, hh * hh);
        const float* arow = alpha + ((size_t)b * KP + j) * NC;
        for (int i = 0; i < KG; ++i) {
            part += arow[gl[i]] * kval(gm[i], pm);
        }
    }
    red[tid] = part;
    __syncthreads();
#pragma unroll
    for (int s = 128; s > 0; s >>= 1) {
        if (tid < s) red[tid] += red[tid + s];
        __syncthreads();
    }
    if (tid == 0) atomicAdd(&acc_pq[b], red[0]);
}

// qq: per image, sum over 1000x1000 pred pairs, w = dot80(alpha_i, alpha_j).
// Triangular tile enumeration: tile (it,jt), jt>=it; off-diagonal tiles weighted 2x.
// LDS alpha tiles with XOR float4-slot swizzle, 4x4 register micro-tile / thread.
__global__ __launch_bounds__(256) void qq_kernel(const float* __restrict__ pb,
                                                 const float* __restrict__ alpha,
                                                 float* __restrict__ acc_qq) {
    __shared__ float la[64 * LSTR];
    __shared__ float lb[64 * LSTR];
    __shared__ float4 am[64];
    __shared__ float4 bm[64];
    __shared__ float red[256];

    int bi = blockIdx.x;
    int b = bi / NPAIR;
    int t = bi - b * NPAIR;
    int it = 0, rem = t;
    while (rem >= NT - it) { rem -= NT - it; ++it; }
    int jt = it + rem;
    int i0 = it * 64, j0 = jt * 64;

    int tid = threadIdx.x;

    // stage per-row params (m, v)
    if (tid < 128) {
        int side = tid >> 6, r = tid & 63;
        int gi = (side ? j0 : i0) + r;
        float4 v;
        if (gi < KP) {
            float4 x = ((const float4*)pb)[b * KP + gi];
            float hw = x.z * 0.5f, hh = x.w * 0.5f;
            v = make_float4(x.x, x.y, hw * hw, hh * hh);
        } else {
            v = make_float4(0.0f, 0.0f, 1.0f, 1.0f);
        }
        if (side) bm[r] = v; else am[r] = v;
    }

    // stage alpha tiles (coalesced global float4 reads, swizzled LDS writes)
    const float4* A4 = (const float4*)alpha;
#pragma unroll
    for (int side = 0; side < 2; ++side) {
        int base0 = side ? j0 : i0;
        float* L = side ? lb : la;
        for (int idx = tid; idx < 64 * 20; idx += 256) {
            int r = idx / 20;
            int q = idx - r * 20;
            int gi = base0 + r;
            float4 v = make_float4(0.0f, 0.0f, 0.0f, 0.0f);
            if (gi < KP) v = A4[((size_t)b * KP + gi) * 20 + q];
            int slot = q ^ ((r >> 2) & 7);
            *(float4*)&L[r * LSTR + slot * 4] = v;
        }
    }
    __syncthreads();

    int tx = tid & 15, ty = tid >> 4;    // 16x16 thread grid, 4x4 micro-tile
    float acc4[4][4];
#pragma unroll
    for (int r = 0; r < 4; ++r)
#pragma unroll
        for (int s = 0; s < 4; ++s) acc4[r][s] = 0.0f;

    int sa = ty & 7;   // (i>>2)&7 for i = 4*ty+k
    int sb = tx & 7;   // (j>>2)&7 for j = 4*tx+k
    for (int c4 = 0; c4 < 20; ++c4) {
        int ca = (c4 ^ sa) * 4;
        int cb = (c4 ^ sb) * 4;
        float4 av[4], bv[4];
#pragma unroll
        for (int k = 0; k < 4; ++k) {
            av[k] = *(const float4*)&la[(4 * ty + k) * LSTR + ca];
            bv[k] = *(const float4*)&lb[(4 * tx + k) * LSTR + cb];
        }
#pragma unroll
        for (int r = 0; r < 4; ++r)
#pragma unroll
            for (int s = 0; s < 4; ++s)
                acc4[r][s] += av[r].x * bv[s].x + av[r].y * bv[s].y +
                              av[r].z * bv[s].z + av[r].w * bv[s].w;
    }

    // epilogue: K_ij per pair, weight off-diagonal tiles by 2
    float part = 0.0f;
#pragma unroll
    for (int r = 0; r < 4; ++r) {
        float4 pi = am[4 * ty + r];
#pragma unroll
        for (int s = 0; s < 4; ++s) {
            part += acc4[r][s] * kval(pi, bm[4 * tx + s]);
        }
    }
    if (jt != it) part *= 2.0f;

    red[tid] = part;
    __syncthreads();
#pragma unroll
    for (int s = 128; s > 0; s >>= 1) {
        if (tid < s) red[tid] += red[tid + s];
        __syncthreads();
    }
    if (tid == 0) atomicAdd(&acc_qq[b], red[0]);
}

__global__ void final_kernel(const float* __restrict__ acc, float* __restrict__ out) {
    int lane = threadIdx.x;
    float v = 0.0f;
    if (lane < BS) {
        float pq = acc[lane];
        float pp = acc[32 + lane];
        float qq = acc[64 + lane];
        v = 2.0f * logf(pq) - logf(pp) - logf(qq);
    }
    v = wave_reduce_sum(v);
    if (lane == 0) out[0] = -v;
}

extern "C" void kernel_launch(void* const* d_in, const int* in_sizes, int n_in,
                              void* d_out, int out_size, void* d_ws, size_t ws_size,
                              hipStream_t stream) {
    (void)in_sizes; (void)n_in; (void)out_size; (void)ws_size;
    const float* pred_bb  = (const float*)d_in[0];
    const float* pred_lab = (const float*)d_in[1];
    const float* gt_bb    = (const float*)d_in[2];
    const int*   gt_lab   = (const int*)d_in[3];
    float* out = (float*)d_out;

    float* alpha = (float*)d_ws;                      // BS*KP*NC floats = 10.24 MB
    float* acc = alpha + (size_t)BS * KP * NC;        // pq[32], pp[32], qq[32]
    float* acc_pq = acc;
    float* acc_pp = acc + 32;
    float* acc_qq = acc + 64;

    hipLaunchKernelGGL(init_kernel, dim3(1), dim3(128), 0, stream, acc);
    hipLaunchKernelGGL(alpha_kernel, dim3(BS * KP / 4), dim3(256), 0, stream, pred_lab, alpha);
    hipLaunchKernelGGL(pp_kernel, dim3(BS), dim3(256), 0, stream, gt_bb, gt_lab, acc_pp);
    hipLaunchKernelGGL(pq_kernel, dim3(4, BS), dim3(256), 0, stream,
                       pred_bb, alpha, gt_bb, gt_lab, acc_pq);
    hipLaunchKernelGGL(qq_kernel, dim3(BS * NPAIR), dim3(256), 0, stream,
                       pred_bb, alpha, acc_qq);
    hipLaunchKernelGGL(final_kernel, dim3(1), dim3(64), 0, stream, acc, out);
}

// Round 2
// 179.122 us; speedup vs baseline: 1.0620x; 1.0620x over previous
//
#include <hip/hip_runtime.h>
#include <math.h>

#define BS 32
#define KP 1000
#define KG 100
#define NC 80
#define NT8 8            // ceil(KP/128)
#define NPAIR 36         // NT8*(NT8+1)/2
#define LS 64            // LDS row stride in floats for a 40-col chunk (16 float4 slots; slot = q ^ ((row>>3)&7) <= 15)

__device__ __forceinline__ float wave_reduce_sum(float v) {
#pragma unroll
    for (int m = 32; m > 0; m >>= 1) v += __shfl_xor(v, m, 64);
    return v;
}
__device__ __forceinline__ float wave_reduce_max(float v) {
#pragma unroll
    for (int m = 32; m > 0; m >>= 1) v = fmaxf(v, __shfl_xor(v, m, 64));
    return v;
}

// K_ij = N(m_i; m_j, v_i+v_j) for 2 independent dims. a,b = (mx, my, vx, vy)
__device__ __forceinline__ float kval(float4 a, float4 b) {
    float Sx = a.z + b.z, Sy = a.w + b.w;
    float ix = 1.0f / Sx, iy = 1.0f / Sy;
    float dx = a.x - b.x, dy = a.y - b.y;
    return 0.15915494309189535f * sqrtf(ix * iy) *
           __expf(-0.5f * (dx * dx * ix + dy * dy * iy));
}

// pred_alpha[row][c] = sigmoid(logits[80]) * softmax(logits[0..79])
// one wave per row; 4 waves (256 threads) per block. Block 0 also zeroes acc[96].
__global__ __launch_bounds__(256) void alpha_kernel(const float* __restrict__ pl,
                                                    float* __restrict__ alpha,
                                                    float* __restrict__ acc) {
    if (blockIdx.x == 0 && threadIdx.x < 96) acc[threadIdx.x] = 0.0f;
    int wave = threadIdx.x >> 6;
    int lane = threadIdx.x & 63;
    int row = blockIdx.x * 4 + wave;                  // < BS*KP = 32000
    const float* x = pl + (size_t)row * (NC + 1);
    float l0 = x[lane];
    float l1;
    if (lane < 16) l1 = x[64 + lane]; else l1 = -1e30f;
    float obj = x[NC];
    float m = wave_reduce_max(fmaxf(l0, l1));
    float e0 = __expf(l0 - m);
    float e1 = (lane < 16) ? __expf(l1 - m) : 0.0f;
    float s = wave_reduce_sum(e0 + e1);
    float sig = 1.0f / (1.0f + __expf(-obj));
    float sc = sig / s;
    float* o = alpha + (size_t)row * NC;
    o[lane] = e0 * sc;
    if (lane < 16) o[64 + lane] = e1 * sc;
}

// Fused pp + pq. grid (5, BS): blockIdx.x<4 -> pq chunk of 256 pred j's; ==4 -> pp.
__global__ __launch_bounds__(256) void ppq_kernel(const float* __restrict__ pb,
                                                  const float* __restrict__ alpha,
                                                  const float* __restrict__ gtb,
                                                  const int* __restrict__ gtl,
                                                  float* __restrict__ acc_pq,
                                                  float* __restrict__ acc_pp) {
    __shared__ float4 gm[KG];
    __shared__ int gl[KG];
    __shared__ float red[256];
    int b = blockIdx.y;
    int tid = threadIdx.x;
    if (tid < KG) {
        float4 x = ((const float4*)gtb)[b * KG + tid];
        gm[tid] = make_float4(x.x, x.y, 0.25f * x.z * x.z, 0.25f * x.w * x.w);
        gl[tid] = gtl[b * KG + tid];
    }
    __syncthreads();
    float part = 0.0f;
    if (blockIdx.x < 4) {
        int j = blockIdx.x * 256 + tid;
        if (j < KP) {
            float4 x = ((const float4*)pb)[b * KP + j];
            float4 pm = make_float4(x.x, x.y, 0.25f * x.z * x.z, 0.25f * x.w * x.w);
            const float* arow = alpha + ((size_t)b * KP + j) * NC;
#pragma unroll 4
            for (int i = 0; i < KG; ++i) {
                part += arow[gl[i]] * kval(gm[i], pm);
            }
        }
    } else {
        for (int p = tid; p < KG * KG; p += 256) {
            int i = p / KG;
            int j = p - i * KG;
            if (gl[i] == gl[j]) part += kval(gm[i], gm[j]);
        }
    }
    red[tid] = part;
    __syncthreads();
#pragma unroll
    for (int s = 128; s > 0; s >>= 1) {
        if (tid < s) red[tid] += red[tid + s];
        __syncthreads();
    }
    if (tid == 0) {
        if (blockIdx.x < 4) atomicAdd(&acc_pq[b], red[0]);
        else acc_pp[b] = red[0];
    }
}

// qq: per image, sum over 1000x1000 pred pairs, w = dot80(alpha_i, alpha_j).
// 128x128 tile per block, triangular tile enumeration (off-diag x2).
// K split in two 40-col chunks staged in LDS (slot XOR (row>>3)&7 swizzle ->
// conflict-free 8-address b128 reads). 8x8 lane grid, 8x8 register micro-tile.
__global__ __launch_bounds__(256, 2) void qq_kernel(const float* __restrict__ pb,
                                                    const float* __restrict__ alpha,
                                                    float* __restrict__ acc_qq) {
    __shared__ float la[128 * LS];
    __shared__ float lb[128 * LS];
    __shared__ float prm[8][128];   // [0..3]=a-side mx,my,vx,vy ; [4..7]=b-side
    __shared__ float red[256];

    int bi = blockIdx.x;
    int b = bi / NPAIR;
    int t = bi - b * NPAIR;
    int it = 0, rem = t;
    while (rem >= NT8 - it) { rem -= NT8 - it; ++it; }
    int jt = it + rem;
    int i0 = it * 128, j0 = jt * 128;

    int tid = threadIdx.x;

    // stage per-row params (m, v) as SoA (conflict-free b32 epilogue reads)
    {
        int side = tid >> 7, r = tid & 127;
        int gi = (side ? j0 : i0) + r;
        float4 v = make_float4(0.0f, 0.0f, 1.0f, 1.0f);
        if (gi < KP) {
            float4 x = ((const float4*)pb)[b * KP + gi];
            v = make_float4(x.x, x.y, 0.25f * x.z * x.z, 0.25f * x.w * x.w);
        }
        prm[side * 4 + 0][r] = v.x;
        prm[side * 4 + 1][r] = v.y;
        prm[side * 4 + 2][r] = v.z;
        prm[side * 4 + 3][r] = v.w;
    }

    int lane = tid & 63, w = tid >> 6;
    int wy = w >> 1, wx = w & 1;
    int tx = lane & 7, ty = lane >> 3;
    int ra = wy * 64 + ty * 8;     // a-side row base (8 rows)
    int rb = wx * 64 + tx * 8;     // b-side row base (8 cols)

    float acc[8][8];
#pragma unroll
    for (int r = 0; r < 8; ++r)
#pragma unroll
        for (int s = 0; s < 8; ++s) acc[r][s] = 0.0f;

    const float4* A4 = (const float4*)alpha;
    for (int c = 0; c < 2; ++c) {
        __syncthreads();   // protect LDS from previous chunk's readers
#pragma unroll
        for (int side = 0; side < 2; ++side) {
            int base0 = side ? j0 : i0;
            float* L = side ? lb : la;
#pragma unroll
            for (int k = 0; k < 5; ++k) {
                int idx = tid + k * 256;          // 0..1279
                int r = idx / 10, q = idx - r * 10;
                int gi = base0 + r;
                float4 v = make_float4(0.0f, 0.0f, 0.0f, 0.0f);
                if (gi < KP) v = A4[((size_t)b * KP + gi) * 20 + c * 10 + q];
                int slot = q ^ ((r >> 3) & 7);
                *(float4*)&L[r * LS + slot * 4] = v;
            }
        }
        __syncthreads();

        for (int m = 0; m < 10; ++m) {
            int sa = (m ^ ty) << 2;
            int sb = (m ^ tx) << 2;
            float4 av[8], bv[8];
#pragma unroll
            for (int r = 0; r < 8; ++r) av[r] = *(const float4*)&la[(ra + r) * LS + sa];
#pragma unroll
            for (int s = 0; s < 8; ++s) bv[s] = *(const float4*)&lb[(rb + s) * LS + sb];
#pragma unroll
            for (int r = 0; r < 8; ++r)
#pragma unroll
                for (int s = 0; s < 8; ++s)
                    acc[r][s] += av[r].x * bv[s].x + av[r].y * bv[s].y +
                                 av[r].z * bv[s].z + av[r].w * bv[s].w;
        }
    }

    // epilogue: K_ij per pair, weight off-diagonal tiles by 2
    float4 pjv[8];
#pragma unroll
    for (int s = 0; s < 8; ++s)
        pjv[s] = make_float4(prm[4][rb + s], prm[5][rb + s], prm[6][rb + s], prm[7][rb + s]);
    float part = 0.0f;
#pragma unroll
    for (int r = 0; r < 8; ++r) {
        float4 pi = make_float4(prm[0][ra + r], prm[1][ra + r], prm[2][ra + r], prm[3][ra + r]);
#pragma unroll
        for (int s = 0; s < 8; ++s) {
            part += acc[r][s] * kval(pi, pjv[s]);
        }
    }
    if (jt != it) part *= 2.0f;

    red[tid] = part;
    __syncthreads();
#pragma unroll
    for (int s = 128; s > 0; s >>= 1) {
        if (tid < s) red[tid] += red[tid + s];
        __syncthreads();
    }
    if (tid == 0) atomicAdd(&acc_qq[b], red[0]);
}

__global__ void final_kernel(const float* __restrict__ acc, float* __restrict__ out) {
    int lane = threadIdx.x;
    float v = 0.0f;
    if (lane < BS) {
        float pq = acc[lane];
        float pp = acc[32 + lane];
        float qq = acc[64 + lane];
        v = 2.0f * logf(pq) - logf(pp) - logf(qq);
    }
    v = wave_reduce_sum(v);
    if (lane == 0) out[0] = -v;
}

extern "C" void kernel_launch(void* const* d_in, const int* in_sizes, int n_in,
                              void* d_out, int out_size, void* d_ws, size_t ws_size,
                              hipStream_t stream) {
    (void)in_sizes; (void)n_in; (void)out_size; (void)ws_size;
    const float* pred_bb  = (const float*)d_in[0];
    const float* pred_lab = (const float*)d_in[1];
    const float* gt_bb    = (const float*)d_in[2];
    const int*   gt_lab   = (const int*)d_in[3];
    float* out = (float*)d_out;

    float* alpha = (float*)d_ws;                      // BS*KP*NC floats = 10.24 MB
    float* acc = alpha + (size_t)BS * KP * NC;        // pq[32], pp[32], qq[32]
    float* acc_pq = acc;
    float* acc_pp = acc + 32;
    float* acc_qq = acc + 64;

    hipLaunchKernelGGL(alpha_kernel, dim3(BS * KP / 4), dim3(256), 0, stream,
                       pred_lab, alpha, acc);
    hipLaunchKernelGGL(ppq_kernel, dim3(5, BS), dim3(256), 0, stream,
                       pred_bb, alpha, gt_bb, gt_lab, acc_pq, acc_pp);
    hipLaunchKernelGGL(qq_kernel, dim3(BS * NPAIR), dim3(256), 0, stream,
                       pred_bb, alpha, acc_qq);
    hipLaunchKernelGGL(final_kernel, dim3(1), dim3(64), 0, stream, acc, out);
}